// Round 10
// baseline (207.174 us; speedup 1.0000x reference)
//
#include <hip/hip_runtime.h>
#include <math.h>

#define GD 128   // dynamic/feature dim
#define ELLW 64  // ELL width; max in-degree of restricted rows (avg ~10, Poisson tail << 64)
#define NSEG 512 // passA/passB grid size == number of private 1-hop segments
#define NPART 8  // partial blocks per b in fused3

// ---------------- pass A: 1-hop expansion into private per-block segments ----------------
// codeid set in LDS bitmap; hits appended to private segment; bcnt written unconditionally.
// Also zeroes cntarr+gx2buf+done inline and computes the hoisted patient GEMV (last block).
__global__ __launch_bounds__(256) void passA(const int* __restrict__ codeid, int B,
                                             const int* __restrict__ erow,
                                             const int* __restrict__ ecol, int E,
                                             int N, int MAXH, int nzero,
                                             int* __restrict__ list1,
                                             int* __restrict__ bcnt,
                                             int* __restrict__ zbase,
                                             const float* __restrict__ patient,
                                             const float* __restrict__ W_ih,
                                             const float* __restrict__ b_ih,
                                             const float* __restrict__ b_hh,
                                             const int* __restrict__ patientid,
                                             float* __restrict__ pc) {
    extern __shared__ unsigned int bm[];  // (N+31)/32 words
    __shared__ int lcnt;
    int t = threadIdx.x;
    int words = (N + 31) >> 5;
    for (int i = t; i < words; i += 256) bm[i] = 0;
    if (t == 0) lcnt = 0;
    __syncthreads();
    for (int i = t; i < B; i += 256) {
        int c = codeid[i];
        atomicOr(&bm[c >> 5], 1u << (c & 31));
    }
    __syncthreads();

    if (blockIdx.x == gridDim.x - 1 && t < GD) {
        // pc = b_ih + b_hh + patient[pid] @ W_ih[:, :128]^T (identical for all b)
        int pid = patientid[0];
        const float* wih = W_ih + (size_t)t * 257;
        const float* pp = patient + (size_t)pid * GD;
        float a0 = 0.f, a1 = 0.f;
#pragma unroll 8
        for (int k = 0; k < GD; k += 2) {
            a0 += pp[k] * wih[k];
            a1 += pp[k + 1] * wih[k + 1];
        }
        pc[t] = b_ih[t] + b_hh[t] + a0 + a1;
    }

    int gid = blockIdx.x * 256 + t, gs = gridDim.x * 256;
    for (int i = gid; i < nzero; i += gs) zbase[i] = 0;  // cntarr + gx2buf + done
    // E-scan: append 1-hop destinations of codeid-rooted edges to private segment
    int* seg = list1 + (size_t)blockIdx.x * MAXH;
    for (int e = gid; e < E; e += gs) {
        int r = erow[e];
        if ((bm[r >> 5] >> (r & 31)) & 1u) {
            int idx = atomicAdd(&lcnt, 1);  // LDS atomic
            seg[idx] = ecol[e];
        }
    }
    __syncthreads();
    if (t == 0) bcnt[blockIdx.x] = lcnt;
}

// ---------------- pass B: U-bitmap (codeid U segments) -> restricted ELL build ----------------
__global__ __launch_bounds__(256) void passB(const int* __restrict__ erow,
                                             const int* __restrict__ ecol,
                                             const float* __restrict__ ev, int E,
                                             const int* __restrict__ codeid, int B,
                                             const int* __restrict__ list1,
                                             const int* __restrict__ bcnt,
                                             int MAXH, int N,
                                             int* __restrict__ cnt,
                                             int* __restrict__ ellc,
                                             float* __restrict__ ellv) {
    extern __shared__ unsigned int bm[];  // (N+31)/32 words
    int t = threadIdx.x;
    int words = (N + 31) >> 5;
    for (int i = t; i < words; i += 256) bm[i] = 0;
    __syncthreads();
    for (int i = t; i < B; i += 256) {
        int c = codeid[i];
        atomicOr(&bm[c >> 5], 1u << (c & 31));
    }
    for (int s = t; s < NSEG; s += 256) {
        int c = bcnt[s];
        const int* seg = list1 + (size_t)s * MAXH;
        for (int k = 0; k < c; ++k) {
            int u = seg[k];
            atomicOr(&bm[u >> 5], 1u << (u & 31));
        }
    }
    __syncthreads();

    int gid = blockIdx.x * 256 + t, gs = gridDim.x * 256;
    for (int e = gid; e < E; e += gs) {
        int r = erow[e];
        if ((bm[r >> 5] >> (r & 31)) & 1u) {
            int idx = atomicAdd(&cnt[r], 1);  // distributed: ~10 per address
            if (idx < ELLW) {
                ellc[(size_t)r * ELLW + idx] = ecol[e];
                ellv[(size_t)r * ELLW + idx] = ev[e];
            }
        }
    }
}

// ---------------- fused3: layer1 partials (B*8 blocks) + last-arrival tail ----------------
// Block (b, p): computes x1 for neighbors i = p, p+8, ... of cid_b; accumulates
// partial sum(sev_i * x1_i) into gx2buf[b] via device atomics. 8th arrival for b
// (proof all partials visible) runs W2 GEMV + RNNCell + L2 norm.
__global__ __launch_bounds__(256) void fused3(const float* __restrict__ X,
                                              const float* __restrict__ W1,
                                              const float* __restrict__ W2,
                                              const float* __restrict__ init,
                                              const int* __restrict__ cnt,
                                              const int* __restrict__ ellc,
                                              const float* __restrict__ ellv,
                                              const int* __restrict__ codeid,
                                              const float* __restrict__ timediffs,
                                              const float* __restrict__ features,
                                              const float* __restrict__ W_ih,
                                              const float* __restrict__ W_hh,
                                              const float* __restrict__ pc,
                                              float* __restrict__ gx2buf,
                                              int* __restrict__ done,
                                              float* __restrict__ out) {
    __shared__ int   sec[ELLW];
    __shared__ float sev[ELLW];
    __shared__ int   ncnt2[2];
    __shared__ int   nec[2][ELLW];
    __shared__ float nev[2][ELLW];
    __shared__ float gxs[2][GD];
    __shared__ float p2[2][GD];
    __shared__ int   lastflag;

    int b = blockIdx.x >> 3, p = blockIdx.x & (NPART - 1);
    int t = threadIdx.x;
    int sub = t >> 7, j = t & 127;
    int cid = codeid[b];
    int c = cnt[cid]; if (c > ELLW) c = ELLW;

    if (t < c) { sec[t] = ellc[(size_t)cid * ELLW + t]; sev[t] = ellv[(size_t)cid * ELLW + t]; }
    __syncthreads();

    // layer-1 partials for assigned neighbors (stride NPART, 2 per round)
    float a2 = 0.f;
    for (int base = p; base < c; base += NPART * 2) {
        int i0 = base, i1 = base + NPART;
        bool v1 = (i1 < c);
        if (t == 0) ncnt2[0] = min(cnt[sec[i0]], ELLW);
        if (t == 1 && v1) ncnt2[1] = min(cnt[sec[i1]], ELLW);
        // stage both neighbor ELL rows (64 entries each)
        if (j < ELLW) {
            if (sub == 0) {
                nec[0][j] = ellc[(size_t)sec[i0] * ELLW + j];
                nev[0][j] = ellv[(size_t)sec[i0] * ELLW + j];
            } else if (v1) {
                nec[1][j] = ellc[(size_t)sec[i1] * ELLW + j];
                nev[1][j] = ellv[(size_t)sec[i1] * ELLW + j];
            }
        }
        __syncthreads();
        int i = sub ? i1 : i0;
        bool act = sub ? v1 : true;
        if (act) {
            int cc = ncnt2[sub];
            float g0 = 0.f, g1 = 0.f, g2 = 0.f, g3 = 0.f;
            int k = 0;
            for (; k + 3 < cc; k += 4) {
                g0 += nev[sub][k]     * X[(size_t)nec[sub][k]     * GD + j];
                g1 += nev[sub][k + 1] * X[(size_t)nec[sub][k + 1] * GD + j];
                g2 += nev[sub][k + 2] * X[(size_t)nec[sub][k + 2] * GD + j];
                g3 += nev[sub][k + 3] * X[(size_t)nec[sub][k + 3] * GD + j];
            }
            for (; k < cc; ++k) g0 += nev[sub][k] * X[(size_t)nec[sub][k] * GD + j];
            gxs[sub][j] = (g0 + g1) + (g2 + g3);
        }
        __syncthreads();
        if (act) {
            float a0 = 0.f, a1 = 0.f, b2 = 0.f, b3 = 0.f;
            const float* gp = gxs[sub];
#pragma unroll 8
            for (int k = 0; k < GD; k += 4) {
                a0 += gp[k]     * W1[(size_t)k       * GD + j];
                a1 += gp[k + 1] * W1[(size_t)(k + 1) * GD + j];
                b2 += gp[k + 2] * W1[(size_t)(k + 2) * GD + j];
                b3 += gp[k + 3] * W1[(size_t)(k + 3) * GD + j];
            }
            float x1v = fmaxf(0.1f * ((a0 + a1) + (b2 + b3))
                              + 0.9f * init[(size_t)sec[i] * GD + j], 0.f);
            a2 += sev[i] * x1v;   // layer-2 gather, in-register
        }
        __syncthreads();  // protect LDS reuse
    }
    p2[sub][j] = a2;
    __syncthreads();
    if (t < GD) {
        float v = p2[0][t] + p2[1][t];
        if (v != 0.f) atomicAdd(gx2buf + (size_t)b * GD + t, v);
    }
    __threadfence();  // release: partials visible before counter bump
    if (t == 0) lastflag = (atomicAdd(&done[b], 1) == NPART - 1);
    __syncthreads();
    if (!lastflag) return;
    __threadfence();  // acquire side

    // ---- tail (one block per b): W2 GEMV + RNNCell + L2 norm ----
    __shared__ float gx2[GD];
    __shared__ float feat[GD];
    __shared__ float ce[GD];
    __shared__ float red[GD];
    if (t < GD) {
        gx2[t] = atomicAdd(gx2buf + (size_t)b * GD + t, 0.f);  // coherent load
        feat[t] = features[(size_t)b * GD + t];
    }
    __syncthreads();

    {   // W2 GEMV: sub covers k in [64*sub, 64*sub+64)
        int kb = sub << 6;
        float a0 = 0.f, a1 = 0.f, b2 = 0.f, b3 = 0.f;
#pragma unroll 8
        for (int k = 0; k < 64; k += 4) {
            a0 += gx2[kb + k]     * W2[(size_t)(kb + k)     * GD + j];
            a1 += gx2[kb + k + 1] * W2[(size_t)(kb + k + 1) * GD + j];
            b2 += gx2[kb + k + 2] * W2[(size_t)(kb + k + 2) * GD + j];
            b3 += gx2[kb + k + 3] * W2[(size_t)(kb + k + 3) * GD + j];
        }
        p2[sub][j] = (a0 + a1) + (b2 + b3);
    }
    __syncthreads();
    if (t < GD)
        ce[t] = fmaxf(0.1f * (p2[0][t] + p2[1][t]) + 0.9f * init[(size_t)cid * GD + t], 0.f);
    __syncthreads();

    {   // RNN partials (feat + ce parts); patient part precomputed in pc[]
        const float* wih = W_ih + (size_t)j * 257;
        const float* whh = W_hh + (size_t)j * GD;
        int kb = sub << 6;
        float a0 = (sub == 0) ? (pc[j] + timediffs[b] * wih[GD]) : 0.f;
        float a1 = 0.f;
#pragma unroll 8
        for (int k = 0; k < 64; k += 2) {
            a0 += feat[kb + k]     * wih[129 + kb + k];
            a1 += feat[kb + k + 1] * wih[129 + kb + k + 1];
        }
#pragma unroll 8
        for (int k = 0; k < 64; k += 2) {
            a0 += ce[kb + k]     * whh[kb + k];
            a1 += ce[kb + k + 1] * whh[kb + k + 1];
        }
        p2[sub][j] = a0 + a1;
    }
    __syncthreads();
    float h = 0.f;
    if (t < GD) {
        h = tanhf(p2[0][t] + p2[1][t]);
        red[t] = h * h;
    }
    __syncthreads();
    for (int s = 64; s > 0; s >>= 1) {
        if (t < s) red[t] += red[t + s];
        __syncthreads();
    }
    if (t < GD) {
        float nrm = fmaxf(sqrtf(red[0]), 1e-12f);
        out[(size_t)b * GD + t] = h / nrm;
    }
}

// ================= launcher (3 launches, no pre-zeroed globals) =================

extern "C" void kernel_launch(void* const* d_in, const int* in_sizes, int n_in,
                              void* d_out, int out_size, void* d_ws, size_t ws_size,
                              hipStream_t stream) {
    const float* code_dynamic = (const float*)d_in[0];
    const float* init_cd      = (const float*)d_in[1];
    const float* patient      = (const float*)d_in[2];
    const float* timediffs    = (const float*)d_in[3];
    const float* features     = (const float*)d_in[4];
    const float* edge_val     = (const float*)d_in[5];
    const float* W1           = (const float*)d_in[6];
    const float* W2           = (const float*)d_in[7];
    const float* W_ih         = (const float*)d_in[8];
    const float* b_ih         = (const float*)d_in[9];
    const float* W_hh         = (const float*)d_in[10];
    const float* b_hh         = (const float*)d_in[11];
    const int* edge_row       = (const int*)d_in[12];
    const int* edge_col       = (const int*)d_in[13];
    const int* codeid         = (const int*)d_in[14];
    const int* patientid      = (const int*)d_in[15];

    int N = in_sizes[0] / GD;   // 60000
    int E = in_sizes[5];        // 600000
    int B = in_sizes[14];       // 256

    // private-segment capacity: max edges one passA block can visit (rounded to 256)
    int MAXH = 256 * ((E + NSEG * 256 - 1) / (NSEG * 256));

    // workspace layout (all 16B-aligned; zeroed region contiguous: cntarr|gx2buf|done)
    int*   ellc   = (int*)d_ws;                          // N*ELLW
    float* ellv   = (float*)(ellc + (size_t)N * ELLW);   // N*ELLW
    int*   cntarr = (int*)(ellv + (size_t)N * ELLW);     // N      (zeroed in passA)
    float* gx2buf = (float*)(cntarr + N);                // B*GD   (zeroed in passA)
    int*   done   = (int*)(gx2buf + (size_t)B * GD);     // B      (zeroed in passA)
    int*   list1  = done + B;                            // NSEG*MAXH
    int*   bcnt   = list1 + (size_t)NSEG * MAXH;         // NSEG
    float* pcbuf  = (float*)(bcnt + NSEG);               // GD

    int nzero = N + B * GD + B;  // cntarr + gx2buf + done, contiguous ints/floats

    size_t bmBytes = (size_t)((N + 31) / 32) * sizeof(unsigned int);  // 7.5 KB @ N=60000

    passA<<<NSEG, 256, bmBytes, stream>>>(codeid, B, edge_row, edge_col, E,
                                          N, MAXH, nzero, list1, bcnt, cntarr,
                                          patient, W_ih, b_ih, b_hh, patientid, pcbuf);
    passB<<<NSEG, 256, bmBytes, stream>>>(edge_row, edge_col, edge_val, E,
                                          codeid, B, list1, bcnt, MAXH, N,
                                          cntarr, ellc, ellv);
    fused3<<<B * NPART, 256, 0, stream>>>(code_dynamic, W1, W2, init_cd,
                                          cntarr, ellc, ellv, codeid, timediffs, features,
                                          W_ih, W_hh, pcbuf, gx2buf, done, (float*)d_out);
}

// Round 11
// 44.413 us; speedup vs baseline: 4.6647x; 4.6647x over previous
//
#include <hip/hip_runtime.h>
#include <math.h>

#define GD 128   // dynamic/feature dim
#define ELLW 64  // ELL width; max in-degree of restricted rows (avg ~10, Poisson tail << 64)
#define NSEG 512 // passA/passB grid size == number of private 1-hop segments
#define NT 8     // neighbors per layer-1 tile in fused12

// ---------------- pass A: 1-hop expansion into private per-block segments ----------------
// codeid set in LDS bitmap; hits appended to private segment; bcnt written unconditionally.
// Also zeroes cntarr inline and computes the hoisted patient GEMV (last block).
__global__ __launch_bounds__(256) void passA(const int* __restrict__ codeid, int B,
                                             const int* __restrict__ erow,
                                             const int* __restrict__ ecol, int E,
                                             int N, int MAXH,
                                             int* __restrict__ list1,
                                             int* __restrict__ bcnt,
                                             int* __restrict__ cntarr,
                                             const float* __restrict__ patient,
                                             const float* __restrict__ W_ih,
                                             const float* __restrict__ b_ih,
                                             const float* __restrict__ b_hh,
                                             const int* __restrict__ patientid,
                                             float* __restrict__ pc) {
    extern __shared__ unsigned int bm[];  // (N+31)/32 words
    __shared__ int lcnt;
    int t = threadIdx.x;
    int words = (N + 31) >> 5;
    for (int i = t; i < words; i += 256) bm[i] = 0;
    if (t == 0) lcnt = 0;
    __syncthreads();
    for (int i = t; i < B; i += 256) {
        int c = codeid[i];
        atomicOr(&bm[c >> 5], 1u << (c & 31));
    }
    __syncthreads();

    if (blockIdx.x == gridDim.x - 1 && t < GD) {
        // pc = b_ih + b_hh + patient[pid] @ W_ih[:, :128]^T (identical for all b)
        int pid = patientid[0];
        const float* wih = W_ih + (size_t)t * 257;
        const float* pp = patient + (size_t)pid * GD;
        float a0 = 0.f, a1 = 0.f;
#pragma unroll 8
        for (int k = 0; k < GD; k += 2) {
            a0 += pp[k] * wih[k];
            a1 += pp[k + 1] * wih[k + 1];
        }
        pc[t] = b_ih[t] + b_hh[t] + a0 + a1;
    }

    int gid = blockIdx.x * 256 + t, gs = gridDim.x * 256;
    for (int i = gid; i < N; i += gs) cntarr[i] = 0;
    // E-scan: append 1-hop destinations of codeid-rooted edges to private segment
    int* seg = list1 + (size_t)blockIdx.x * MAXH;
    for (int e = gid; e < E; e += gs) {
        int r = erow[e];
        if ((bm[r >> 5] >> (r & 31)) & 1u) {
            int idx = atomicAdd(&lcnt, 1);  // LDS atomic
            seg[idx] = ecol[e];
        }
    }
    __syncthreads();
    if (t == 0) bcnt[blockIdx.x] = lcnt;
}

// ---------------- pass B: U-bitmap (codeid U segments) -> restricted ELL build ----------------
__global__ __launch_bounds__(256) void passB(const int* __restrict__ erow,
                                             const int* __restrict__ ecol,
                                             const float* __restrict__ ev, int E,
                                             const int* __restrict__ codeid, int B,
                                             const int* __restrict__ list1,
                                             const int* __restrict__ bcnt,
                                             int MAXH, int N,
                                             int* __restrict__ cnt,
                                             int* __restrict__ ellc,
                                             float* __restrict__ ellv) {
    extern __shared__ unsigned int bm[];  // (N+31)/32 words
    int t = threadIdx.x;
    int words = (N + 31) >> 5;
    for (int i = t; i < words; i += 256) bm[i] = 0;
    __syncthreads();
    for (int i = t; i < B; i += 256) {
        int c = codeid[i];
        atomicOr(&bm[c >> 5], 1u << (c & 31));
    }
    for (int s = t; s < NSEG; s += 256) {
        int c = bcnt[s];
        const int* seg = list1 + (size_t)s * MAXH;
        for (int k = 0; k < c; ++k) {
            int u = seg[k];
            atomicOr(&bm[u >> 5], 1u << (u & 31));
        }
    }
    __syncthreads();

    int gid = blockIdx.x * 256 + t, gs = gridDim.x * 256;
    for (int e = gid; e < E; e += gs) {
        int r = erow[e];
        if ((bm[r >> 5] >> (r & 31)) & 1u) {
            int idx = atomicAdd(&cnt[r], 1);  // distributed: ~10 per address
            if (idx < ELLW) {
                ellc[(size_t)r * ELLW + idx] = ecol[e];
                ellv[(size_t)r * ELLW + idx] = ev[e];
            }
        }
    }
}

// ---------------- fused: layer1 tiled-GEMM + layer2 + RNNCell + L2 norm ----------------
// One block (512 thr = 4 subs x 128) per b; no cross-block sync (round-10 lesson:
// device-scope fences/atomics on non-coherent XCD L2s cost more than a launch).
// Layer 1 per tile of NT=8 neighbors: gather all 8 into LDS, then ONE W1 sweep where
// each W1 load feeds 2 neighbors (thread owns neighbors sub and sub+4 of the tile).
__global__ __launch_bounds__(512) void fused12(const float* __restrict__ X,
                                               const float* __restrict__ W1,
                                               const float* __restrict__ W2,
                                               const float* __restrict__ init,
                                               const int* __restrict__ cnt,
                                               const int* __restrict__ ellc,
                                               const float* __restrict__ ellv,
                                               const int* __restrict__ codeid,
                                               const float* __restrict__ timediffs,
                                               const float* __restrict__ features,
                                               const float* __restrict__ W_ih,
                                               const float* __restrict__ W_hh,
                                               const float* __restrict__ pc,
                                               float* __restrict__ out) {
    __shared__ int   sec[ELLW];
    __shared__ float sev[ELLW];
    __shared__ int   ncnt[NT];
    __shared__ int   nec[NT][ELLW];
    __shared__ float nev[NT][ELLW];
    __shared__ float gxall[NT][GD];
    __shared__ float p2[4][GD];
    __shared__ float gx2[GD];
    __shared__ float feat[GD];
    __shared__ float ce[GD];
    __shared__ float red[GD];

    int b = blockIdx.x, t = threadIdx.x;
    int sub = t >> 7, j = t & 127;
    int cid = codeid[b];
    int c = cnt[cid]; if (c > ELLW) c = ELLW;

    if (t < c) { sec[t] = ellc[(size_t)cid * ELLW + t]; sev[t] = ellv[(size_t)cid * ELLW + t]; }
    if (t < GD) feat[t] = features[(size_t)b * GD + t];
    __syncthreads();

    float a2 = 0.f;  // per-(sub,j) layer-2 partial: sum over owned neighbors of sev*x1
    for (int tb = 0; tb < c; tb += NT) {
        int nt = c - tb; if (nt > NT) nt = NT;
        if (t < NT) ncnt[t] = (t < nt) ? min(cnt[sec[tb + t]], ELLW) : 0;
        __syncthreads();
        {   // stage NT ELL rows, zero-padded (pad -> index 0 / value 0: safe, no-op)
            int i = t >> 6, k = t & 63;
            bool ok = (k < ncnt[i]);
            nec[i][k] = ok ? ellc[(size_t)sec[tb + i] * ELLW + k] : 0;
            nev[i][k] = ok ? ellv[(size_t)sec[tb + i] * ELLW + k] : 0.f;
        }
        __syncthreads();

        // gather 2 neighbors per thread (ia=sub, ib=sub+4): 8 X-row loads in flight
        int ia = sub, ib = sub + 4;
        int cm = max(ncnt[ia], ncnt[ib]);
        cm = (cm + 3) & ~3;  // rows zero-padded -> no guards needed
        float ga0 = 0.f, ga1 = 0.f, ga2 = 0.f, ga3 = 0.f;
        float gb0 = 0.f, gb1 = 0.f, gb2 = 0.f, gb3 = 0.f;
        for (int k = 0; k < cm; k += 4) {
            ga0 += nev[ia][k]     * X[(size_t)nec[ia][k]     * GD + j];
            ga1 += nev[ia][k + 1] * X[(size_t)nec[ia][k + 1] * GD + j];
            ga2 += nev[ia][k + 2] * X[(size_t)nec[ia][k + 2] * GD + j];
            ga3 += nev[ia][k + 3] * X[(size_t)nec[ia][k + 3] * GD + j];
            gb0 += nev[ib][k]     * X[(size_t)nec[ib][k]     * GD + j];
            gb1 += nev[ib][k + 1] * X[(size_t)nec[ib][k + 1] * GD + j];
            gb2 += nev[ib][k + 2] * X[(size_t)nec[ib][k + 2] * GD + j];
            gb3 += nev[ib][k + 3] * X[(size_t)nec[ib][k + 3] * GD + j];
        }
        gxall[ia][j] = (ga0 + ga1) + (ga2 + ga3);
        gxall[ib][j] = (gb0 + gb1) + (gb2 + gb3);
        __syncthreads();

        // ONE W1 sweep for the whole tile: each load feeds both owned neighbors
        float xa0 = 0.f, xa1 = 0.f, xb0 = 0.f, xb1 = 0.f;
#pragma unroll 4
        for (int k = 0; k < GD; k += 2) {
            float w0 = W1[(size_t)k * GD + j];
            float w1 = W1[(size_t)(k + 1) * GD + j];
            xa0 += gxall[ia][k] * w0; xa1 += gxall[ia][k + 1] * w1;
            xb0 += gxall[ib][k] * w0; xb1 += gxall[ib][k + 1] * w1;
        }
        if (tb + ia < c) {
            float x1v = fmaxf(0.1f * (xa0 + xa1)
                              + 0.9f * init[(size_t)sec[tb + ia] * GD + j], 0.f);
            a2 += sev[tb + ia] * x1v;
        }
        if (tb + ib < c) {
            float x1v = fmaxf(0.1f * (xb0 + xb1)
                              + 0.9f * init[(size_t)sec[tb + ib] * GD + j], 0.f);
            a2 += sev[tb + ib] * x1v;
        }
        // next tile's first __syncthreads() protects nec/nev/gxall reuse
    }
    p2[sub][j] = a2;
    __syncthreads();
    if (t < GD) gx2[t] = (p2[0][t] + p2[1][t]) + (p2[2][t] + p2[3][t]);
    __syncthreads();

    // W2 GEMV: sub covers k in [32*sub, 32*sub+32), 4 accumulators
    {
        int kb = sub << 5;
        float a0 = 0.f, a1 = 0.f, b2 = 0.f, b3 = 0.f;
#pragma unroll 8
        for (int k = 0; k < 32; k += 4) {
            a0 += gx2[kb + k]     * W2[(size_t)(kb + k)     * GD + j];
            a1 += gx2[kb + k + 1] * W2[(size_t)(kb + k + 1) * GD + j];
            b2 += gx2[kb + k + 2] * W2[(size_t)(kb + k + 2) * GD + j];
            b3 += gx2[kb + k + 3] * W2[(size_t)(kb + k + 3) * GD + j];
        }
        p2[sub][j] = (a0 + a1) + (b2 + b3);
    }
    __syncthreads();
    if (t < GD)
        ce[t] = fmaxf(0.1f * ((p2[0][t] + p2[1][t]) + (p2[2][t] + p2[3][t]))
                      + 0.9f * init[(size_t)cid * GD + t], 0.f);
    __syncthreads();

    // RNN partials: sub covers k in [32*sub, 32*sub+32) of feat and ce parts
    {
        const float* wih = W_ih + (size_t)j * 257;
        const float* whh = W_hh + (size_t)j * GD;
        int kb = sub << 5;
        float a0 = (sub == 0) ? (pc[j] + timediffs[b] * wih[GD]) : 0.f;
        float a1 = 0.f, b2 = 0.f, b3 = 0.f;
#pragma unroll 8
        for (int k = 0; k < 32; k += 4) {
            a0 += feat[kb + k]     * wih[129 + kb + k];
            a1 += feat[kb + k + 1] * wih[129 + kb + k + 1];
            b2 += feat[kb + k + 2] * wih[129 + kb + k + 2];
            b3 += feat[kb + k + 3] * wih[129 + kb + k + 3];
        }
#pragma unroll 8
        for (int k = 0; k < 32; k += 4) {
            a0 += ce[kb + k]     * whh[kb + k];
            a1 += ce[kb + k + 1] * whh[kb + k + 1];
            b2 += ce[kb + k + 2] * whh[kb + k + 2];
            b3 += ce[kb + k + 3] * whh[kb + k + 3];
        }
        p2[sub][j] = (a0 + a1) + (b2 + b3);
    }
    __syncthreads();
    float h = 0.f;
    if (t < GD) {
        h = tanhf((p2[0][t] + p2[1][t]) + (p2[2][t] + p2[3][t]));
        red[t] = h * h;
    }
    __syncthreads();
    for (int s = 64; s > 0; s >>= 1) {
        if (t < s) red[t] += red[t + s];
        __syncthreads();
    }
    if (t < GD) {
        float nrm = fmaxf(sqrtf(red[0]), 1e-12f);
        out[(size_t)b * GD + t] = h / nrm;
    }
}

// ================= launcher (3 launches, no pre-zeroed globals, no cross-block sync) =====

extern "C" void kernel_launch(void* const* d_in, const int* in_sizes, int n_in,
                              void* d_out, int out_size, void* d_ws, size_t ws_size,
                              hipStream_t stream) {
    const float* code_dynamic = (const float*)d_in[0];
    const float* init_cd      = (const float*)d_in[1];
    const float* patient      = (const float*)d_in[2];
    const float* timediffs    = (const float*)d_in[3];
    const float* features     = (const float*)d_in[4];
    const float* edge_val     = (const float*)d_in[5];
    const float* W1           = (const float*)d_in[6];
    const float* W2           = (const float*)d_in[7];
    const float* W_ih         = (const float*)d_in[8];
    const float* b_ih         = (const float*)d_in[9];
    const float* W_hh         = (const float*)d_in[10];
    const float* b_hh         = (const float*)d_in[11];
    const int* edge_row       = (const int*)d_in[12];
    const int* edge_col       = (const int*)d_in[13];
    const int* codeid         = (const int*)d_in[14];
    const int* patientid      = (const int*)d_in[15];

    int N = in_sizes[0] / GD;   // 60000
    int E = in_sizes[5];        // 600000
    int B = in_sizes[14];       // 256

    // private-segment capacity: max edges one passA block can visit (rounded to 256)
    int MAXH = 256 * ((E + NSEG * 256 - 1) / (NSEG * 256));

    // workspace layout (all 16B-aligned)
    int*   ellc   = (int*)d_ws;                          // N*ELLW
    float* ellv   = (float*)(ellc + (size_t)N * ELLW);   // N*ELLW
    int*   cntarr = (int*)(ellv + (size_t)N * ELLW);     // N (zeroed inside passA)
    int*   list1  = cntarr + N;                          // NSEG*MAXH
    int*   bcnt   = list1 + (size_t)NSEG * MAXH;         // NSEG
    float* pcbuf  = (float*)(bcnt + NSEG);               // GD

    size_t bmBytes = (size_t)((N + 31) / 32) * sizeof(unsigned int);  // 7.5 KB @ N=60000

    passA<<<NSEG, 256, bmBytes, stream>>>(codeid, B, edge_row, edge_col, E,
                                          N, MAXH, list1, bcnt, cntarr,
                                          patient, W_ih, b_ih, b_hh, patientid, pcbuf);
    passB<<<NSEG, 256, bmBytes, stream>>>(edge_row, edge_col, edge_val, E,
                                          codeid, B, list1, bcnt, MAXH, N,
                                          cntarr, ellc, ellv);
    fused12<<<B, 512, 0, stream>>>(code_dynamic, W1, W2, init_cd,
                                   cntarr, ellc, ellv, codeid, timediffs, features,
                                   W_ih, W_hh, pcbuf, (float*)d_out);
}

// Round 13
// 43.678 us; speedup vs baseline: 4.7433x; 1.0168x over previous
//
#include <hip/hip_runtime.h>
#include <math.h>

#define GD 128   // dynamic/feature dim
#define ELLW 64  // ELL width; max in-degree of restricted rows (avg ~10, Poisson tail << 64)
#define NSEG 512 // passA/passB grid size == number of private 1-hop segments
#define NT 16    // neighbors per layer-1 tile in fused12 (c<=16 -> single tile round)

// ---------------- pass A: 1-hop expansion into private per-block segments ----------------
// codeid set in LDS bitmap; hits appended to private segment; bcnt written unconditionally.
// Also zeroes cntarr inline (int4) and computes the hoisted patient GEMV (last block).
__global__ __launch_bounds__(256) void passA(const int* __restrict__ codeid, int B,
                                             const int* __restrict__ erow,
                                             const int* __restrict__ ecol, int E,
                                             int N, int MAXH,
                                             int* __restrict__ list1,
                                             int* __restrict__ bcnt,
                                             int* __restrict__ cntarr,
                                             const float* __restrict__ patient,
                                             const float* __restrict__ W_ih,
                                             const float* __restrict__ b_ih,
                                             const float* __restrict__ b_hh,
                                             const int* __restrict__ patientid,
                                             float* __restrict__ pc) {
    extern __shared__ unsigned int bm[];  // (N+31)/32 words
    __shared__ int lcnt;
    int t = threadIdx.x;
    int words = (N + 31) >> 5;
    for (int i = t; i < words; i += 256) bm[i] = 0;
    if (t == 0) lcnt = 0;
    __syncthreads();
    for (int i = t; i < B; i += 256) {
        int c = codeid[i];
        atomicOr(&bm[c >> 5], 1u << (c & 31));
    }
    __syncthreads();

    if (blockIdx.x == gridDim.x - 1 && t < GD) {
        // pc = b_ih + b_hh + patient[pid] @ W_ih[:, :128]^T (identical for all b)
        int pid = patientid[0];
        const float* wih = W_ih + (size_t)t * 257;
        const float* pp = patient + (size_t)pid * GD;
        float a0 = 0.f, a1 = 0.f;
#pragma unroll 8
        for (int k = 0; k < GD; k += 2) {
            a0 += pp[k] * wih[k];
            a1 += pp[k + 1] * wih[k + 1];
        }
        pc[t] = b_ih[t] + b_hh[t] + a0 + a1;
    }

    int gid = blockIdx.x * 256 + t, gs = gridDim.x * 256;
    {   // int4 zero of cntarr (N multiple of 4)
        int4* z = (int4*)cntarr;
        int n4 = N >> 2;
        for (int i = gid; i < n4; i += gs) z[i] = make_int4(0, 0, 0, 0);
    }
    // vectorized E-scan: append 1-hop destinations of codeid-rooted edges
    int* seg = list1 + (size_t)blockIdx.x * MAXH;
    const int4* erow4 = (const int4*)erow;
    int E4 = E >> 2;
    for (int q = gid; q < E4; q += gs) {
        int4 r4 = erow4[q];
        int e = q << 2;
        if ((bm[r4.x >> 5] >> (r4.x & 31)) & 1u) seg[atomicAdd(&lcnt, 1)] = ecol[e];
        if ((bm[r4.y >> 5] >> (r4.y & 31)) & 1u) seg[atomicAdd(&lcnt, 1)] = ecol[e + 1];
        if ((bm[r4.z >> 5] >> (r4.z & 31)) & 1u) seg[atomicAdd(&lcnt, 1)] = ecol[e + 2];
        if ((bm[r4.w >> 5] >> (r4.w & 31)) & 1u) seg[atomicAdd(&lcnt, 1)] = ecol[e + 3];
    }
    for (int e = (E4 << 2) + gid; e < E; e += gs) {  // tail (E%4)
        int r = erow[e];
        if ((bm[r >> 5] >> (r & 31)) & 1u) seg[atomicAdd(&lcnt, 1)] = ecol[e];
    }
    __syncthreads();
    if (t == 0) bcnt[blockIdx.x] = lcnt;
}

// ---------------- pass B: U-bitmap (codeid U segments) -> restricted ELL build ----------------
__global__ __launch_bounds__(256) void passB(const int* __restrict__ erow,
                                             const int* __restrict__ ecol,
                                             const float* __restrict__ ev, int E,
                                             const int* __restrict__ codeid, int B,
                                             const int* __restrict__ list1,
                                             const int* __restrict__ bcnt,
                                             int MAXH, int N,
                                             int* __restrict__ cnt,
                                             int* __restrict__ ellc,
                                             float* __restrict__ ellv) {
    extern __shared__ unsigned int bm[];  // (N+31)/32 words
    int t = threadIdx.x;
    int words = (N + 31) >> 5;
    for (int i = t; i < words; i += 256) bm[i] = 0;
    __syncthreads();
    for (int i = t; i < B; i += 256) {
        int c = codeid[i];
        atomicOr(&bm[c >> 5], 1u << (c & 31));
    }
    for (int s = t; s < NSEG; s += 256) {
        int c = bcnt[s];
        const int* seg = list1 + (size_t)s * MAXH;
        for (int k = 0; k < c; ++k) {
            int u = seg[k];
            atomicOr(&bm[u >> 5], 1u << (u & 31));
        }
    }
    __syncthreads();

    int gid = blockIdx.x * 256 + t, gs = gridDim.x * 256;
    const int4* erow4 = (const int4*)erow;
    int E4 = E >> 2;
    for (int q = gid; q < E4; q += gs) {
        int4 r4 = erow4[q];
        int e = q << 2;
        int rr[4] = { r4.x, r4.y, r4.z, r4.w };
#pragma unroll 4
        for (int u = 0; u < 4; ++u) {
            int r = rr[u];
            if ((bm[r >> 5] >> (r & 31)) & 1u) {
                int idx = atomicAdd(&cnt[r], 1);  // distributed: ~10 per address
                if (idx < ELLW) {
                    ellc[(size_t)r * ELLW + idx] = ecol[e + u];
                    ellv[(size_t)r * ELLW + idx] = ev[e + u];
                }
            }
        }
    }
    for (int e = (E4 << 2) + gid; e < E; e += gs) {  // tail
        int r = erow[e];
        if ((bm[r >> 5] >> (r & 31)) & 1u) {
            int idx = atomicAdd(&cnt[r], 1);
            if (idx < ELLW) {
                ellc[(size_t)r * ELLW + idx] = ecol[e];
                ellv[(size_t)r * ELLW + idx] = ev[e];
            }
        }
    }
}

// ---------------- fused: layer1 tiled-GEMM (NT=16) + layer2 + RNNCell + L2 norm ----------------
// One block (512 thr = 4 subs x 128) per b; no cross-block sync (round-10 lesson:
// device-scope fences/atomics on non-coherent XCD L2s cost more than a launch).
// Per tile of NT=16 neighbors (c<=16 -> ONE round): gather 4 neighbors/thread
// (8 X-row loads in flight), then ONE W1 sweep where each W1 load feeds 4 neighbors.
__global__ __launch_bounds__(512) void fused12(const float* __restrict__ X,
                                               const float* __restrict__ W1,
                                               const float* __restrict__ W2,
                                               const float* __restrict__ init,
                                               const int* __restrict__ cnt,
                                               const int* __restrict__ ellc,
                                               const float* __restrict__ ellv,
                                               const int* __restrict__ codeid,
                                               const float* __restrict__ timediffs,
                                               const float* __restrict__ features,
                                               const float* __restrict__ W_ih,
                                               const float* __restrict__ W_hh,
                                               const float* __restrict__ pc,
                                               float* __restrict__ out) {
    __shared__ int   sec[ELLW];
    __shared__ float sev[ELLW];
    __shared__ int   ncnt[NT];
    __shared__ int   nec[NT][ELLW];     // 4 KB
    __shared__ float nev[NT][ELLW];     // 4 KB
    __shared__ float gxall[NT][GD];     // 8 KB
    __shared__ float p2[4][GD];
    __shared__ float gx2[GD];
    __shared__ float feat[GD];
    __shared__ float ce[GD];
    __shared__ float red[GD];

    int b = blockIdx.x, t = threadIdx.x;
    int sub = t >> 7, j = t & 127;
    int cid = codeid[b];
    int c = cnt[cid]; if (c > ELLW) c = ELLW;

    if (t < c) { sec[t] = ellc[(size_t)cid * ELLW + t]; sev[t] = ellv[(size_t)cid * ELLW + t]; }
    if (t < GD) feat[t] = features[(size_t)b * GD + t];
    __syncthreads();

    float a2 = 0.f;  // per-(sub,j) layer-2 partial: sum over owned neighbors of sev*x1
    for (int tb = 0; tb < c; tb += NT) {
        int nt = c - tb; if (nt > NT) nt = NT;
        if (t < NT) ncnt[t] = (t < nt) ? min(cnt[sec[tb + t]], ELLW) : 0;
        __syncthreads();  // also protects nec/nev/gxall reuse across tiles
        {   // stage NT ELL rows, zero-padded (pad -> index 0 / value 0: safe no-op)
            for (int idx = t; idx < NT * ELLW; idx += 512) {
                int i = idx >> 6, k = idx & 63;
                bool ok = (k < ncnt[i]);
                nec[i][k] = ok ? ellc[(size_t)sec[tb + i] * ELLW + k] : 0;
                nev[i][k] = ok ? ellv[(size_t)sec[tb + i] * ELLW + k] : 0.f;
            }
        }
        __syncthreads();

        // gather 4 neighbors per thread: ia=sub, ib=sub+4, ic=sub+8, id=sub+12
        int ia = sub, ib = sub + 4, ic = sub + 8, id = sub + 12;
        int cm = max(max(ncnt[ia], ncnt[ib]), max(ncnt[ic], ncnt[id]));
        cm = (cm + 1) & ~1;  // rows zero-padded -> no guards
        float ga0 = 0.f, ga1 = 0.f, gb0 = 0.f, gb1 = 0.f;
        float gc0 = 0.f, gc1 = 0.f, gd0 = 0.f, gd1 = 0.f;
        for (int k = 0; k < cm; k += 2) {
            ga0 += nev[ia][k]     * X[(size_t)nec[ia][k]     * GD + j];
            ga1 += nev[ia][k + 1] * X[(size_t)nec[ia][k + 1] * GD + j];
            gb0 += nev[ib][k]     * X[(size_t)nec[ib][k]     * GD + j];
            gb1 += nev[ib][k + 1] * X[(size_t)nec[ib][k + 1] * GD + j];
            gc0 += nev[ic][k]     * X[(size_t)nec[ic][k]     * GD + j];
            gc1 += nev[ic][k + 1] * X[(size_t)nec[ic][k + 1] * GD + j];
            gd0 += nev[id][k]     * X[(size_t)nec[id][k]     * GD + j];
            gd1 += nev[id][k + 1] * X[(size_t)nec[id][k + 1] * GD + j];
        }
        gxall[ia][j] = ga0 + ga1;
        gxall[ib][j] = gb0 + gb1;
        gxall[ic][j] = gc0 + gc1;
        gxall[id][j] = gd0 + gd1;
        __syncthreads();

        // ONE W1 sweep for the whole tile: each W1 load feeds 4 neighbors
        float xa0 = 0.f, xa1 = 0.f, xb0 = 0.f, xb1 = 0.f;
        float xc0 = 0.f, xc1 = 0.f, xd0 = 0.f, xd1 = 0.f;
#pragma unroll 4
        for (int k = 0; k < GD; k += 2) {
            float w0 = W1[(size_t)k * GD + j];
            float w1 = W1[(size_t)(k + 1) * GD + j];
            xa0 += gxall[ia][k] * w0; xa1 += gxall[ia][k + 1] * w1;
            xb0 += gxall[ib][k] * w0; xb1 += gxall[ib][k + 1] * w1;
            xc0 += gxall[ic][k] * w0; xc1 += gxall[ic][k + 1] * w1;
            xd0 += gxall[id][k] * w0; xd1 += gxall[id][k + 1] * w1;
        }
        if (tb + ia < c) {
            float x1v = fmaxf(0.1f * (xa0 + xa1)
                              + 0.9f * init[(size_t)sec[tb + ia] * GD + j], 0.f);
            a2 += sev[tb + ia] * x1v;
        }
        if (tb + ib < c) {
            float x1v = fmaxf(0.1f * (xb0 + xb1)
                              + 0.9f * init[(size_t)sec[tb + ib] * GD + j], 0.f);
            a2 += sev[tb + ib] * x1v;
        }
        if (tb + ic < c) {
            float x1v = fmaxf(0.1f * (xc0 + xc1)
                              + 0.9f * init[(size_t)sec[tb + ic] * GD + j], 0.f);
            a2 += sev[tb + ic] * x1v;
        }
        if (tb + id < c) {
            float x1v = fmaxf(0.1f * (xd0 + xd1)
                              + 0.9f * init[(size_t)sec[tb + id] * GD + j], 0.f);
            a2 += sev[tb + id] * x1v;
        }
    }
    p2[sub][j] = a2;
    __syncthreads();
    if (t < GD) gx2[t] = (p2[0][t] + p2[1][t]) + (p2[2][t] + p2[3][t]);
    __syncthreads();

    // W2 GEMV: sub covers k in [32*sub, 32*sub+32), 4 accumulators
    {
        int kb = sub << 5;
        float a0 = 0.f, a1 = 0.f, b2 = 0.f, b3 = 0.f;
#pragma unroll 8
        for (int k = 0; k < 32; k += 4) {
            a0 += gx2[kb + k]     * W2[(size_t)(kb + k)     * GD + j];
            a1 += gx2[kb + k + 1] * W2[(size_t)(kb + k + 1) * GD + j];
            b2 += gx2[kb + k + 2] * W2[(size_t)(kb + k + 2) * GD + j];
            b3 += gx2[kb + k + 3] * W2[(size_t)(kb + k + 3) * GD + j];
        }
        p2[sub][j] = (a0 + a1) + (b2 + b3);
    }
    __syncthreads();
    if (t < GD)
        ce[t] = fmaxf(0.1f * ((p2[0][t] + p2[1][t]) + (p2[2][t] + p2[3][t]))
                      + 0.9f * init[(size_t)cid * GD + t], 0.f);
    __syncthreads();

    // RNN partials: sub covers k in [32*sub, 32*sub+32) of feat and ce parts
    {
        const float* wih = W_ih + (size_t)j * 257;
        const float* whh = W_hh + (size_t)j * GD;
        int kb = sub << 5;
        float a0 = (sub == 0) ? (pc[j] + timediffs[b] * wih[GD]) : 0.f;
        float a1 = 0.f, b2 = 0.f, b3 = 0.f;
#pragma unroll 8
        for (int k = 0; k < 32; k += 4) {
            a0 += feat[kb + k]     * wih[129 + kb + k];
            a1 += feat[kb + k + 1] * wih[129 + kb + k + 1];
            b2 += feat[kb + k + 2] * wih[129 + kb + k + 2];
            b3 += feat[kb + k + 3] * wih[129 + kb + k + 3];
        }
#pragma unroll 8
        for (int k = 0; k < 32; k += 4) {
            a0 += ce[kb + k]     * whh[kb + k];
            a1 += ce[kb + k + 1] * whh[kb + k + 1];
            b2 += ce[kb + k + 2] * whh[kb + k + 2];
            b3 += ce[kb + k + 3] * whh[kb + k + 3];
        }
        p2[sub][j] = (a0 + a1) + (b2 + b3);
    }
    __syncthreads();
    float h = 0.f;
    if (t < GD) {
        h = tanhf((p2[0][t] + p2[1][t]) + (p2[2][t] + p2[3][t]));
        red[t] = h * h;
    }
    __syncthreads();
    for (int s = 64; s > 0; s >>= 1) {
        if (t < s) red[t] += red[t + s];
        __syncthreads();
    }
    if (t < GD) {
        float nrm = fmaxf(sqrtf(red[0]), 1e-12f);
        out[(size_t)b * GD + t] = h / nrm;
    }
}

// ================= launcher (3 launches, no pre-zeroed globals, no cross-block sync) =====

extern "C" void kernel_launch(void* const* d_in, const int* in_sizes, int n_in,
                              void* d_out, int out_size, void* d_ws, size_t ws_size,
                              hipStream_t stream) {
    const float* code_dynamic = (const float*)d_in[0];
    const float* init_cd      = (const float*)d_in[1];
    const float* patient      = (const float*)d_in[2];
    const float* timediffs    = (const float*)d_in[3];
    const float* features     = (const float*)d_in[4];
    const float* edge_val     = (const float*)d_in[5];
    const float* W1           = (const float*)d_in[6];
    const float* W2           = (const float*)d_in[7];
    const float* W_ih         = (const float*)d_in[8];
    const float* b_ih         = (const float*)d_in[9];
    const float* W_hh         = (const float*)d_in[10];
    const float* b_hh         = (const float*)d_in[11];
    const int* edge_row       = (const int*)d_in[12];
    const int* edge_col       = (const int*)d_in[13];
    const int* codeid         = (const int*)d_in[14];
    const int* patientid      = (const int*)d_in[15];

    int N = in_sizes[0] / GD;   // 60000
    int E = in_sizes[5];        // 600000
    int B = in_sizes[14];       // 256

    // private-segment capacity: worst-case hits per passA block under the VECTORIZED scan:
    // each thread scans ceil(E4/gs) int4-chunks = 4*ceil(E4/gs) edges; 256 threads/block.
    int gs = NSEG * 256;
    int E4 = E >> 2;
    int chunksPerThread = (E4 + gs - 1) / gs;
    int MAXH = 1024 * chunksPerThread + 16;  // 256 thr * 4 edges/chunk + tail slack

    // workspace layout (all 16B-aligned)
    int*   ellc   = (int*)d_ws;                          // N*ELLW
    float* ellv   = (float*)(ellc + (size_t)N * ELLW);   // N*ELLW
    int*   cntarr = (int*)(ellv + (size_t)N * ELLW);     // N (zeroed inside passA)
    int*   list1  = cntarr + N;                          // NSEG*MAXH
    int*   bcnt   = list1 + (size_t)NSEG * MAXH;         // NSEG
    float* pcbuf  = (float*)(bcnt + NSEG);               // GD

    size_t bmBytes = (size_t)((N + 31) / 32) * sizeof(unsigned int);  // 7.5 KB @ N=60000

    passA<<<NSEG, 256, bmBytes, stream>>>(codeid, B, edge_row, edge_col, E,
                                          N, MAXH, list1, bcnt, cntarr,
                                          patient, W_ih, b_ih, b_hh, patientid, pcbuf);
    passB<<<NSEG, 256, bmBytes, stream>>>(edge_row, edge_col, edge_val, E,
                                          codeid, B, list1, bcnt, MAXH, N,
                                          cntarr, ellc, ellv);
    fused12<<<B, 512, 0, stream>>>(code_dynamic, W1, W2, init_cd,
                                   cntarr, ellc, ellv, codeid, timediffs, features,
                                   W_ih, W_hh, pcbuf, (float*)d_out);
}